// Round 7
// baseline (306.104 us; speedup 1.0000x reference)
//
#include <hip/hip_runtime.h>

static constexpr int NN = 50000;
static constexpr int NE = 1600000;
static constexpr int DD = 128;
static constexpr int STRIDE = 72;     // per-node padded edge slots (in-deg mean 32)
static constexpr int NBUCK = 196;     // ceil(NN/256)
static constexpr int CAP = 9000;      // coarse-bucket capacity (mean 8163, +9 sigma)
static constexpr int B1B = 512;       // build1 blocks
static constexpr int CHUNK = NE / B1B; // 3125 (divides exactly)
static constexpr int SCAN_BLOCKS = (NN + 255) / 256;  // 196

typedef __attribute__((ext_vector_type(8))) short short8;
typedef __attribute__((ext_vector_type(4))) float f32x4;

__device__ inline unsigned short f2b(float f) {       // f32 -> bf16 bits, RNE
    unsigned u = __float_as_uint(f);
    return (unsigned short)((u + 0x7FFFu + ((u >> 16) & 1u)) >> 16);
}
__device__ inline float b2f(unsigned short h) {
    return __uint_as_float(((unsigned)h) << 16);
}
__device__ inline unsigned pack2(float lo, float hi) {
    return (unsigned)f2b(lo) | ((unsigned)f2b(hi) << 16);
}
__device__ inline void acc8(float* a, uint4 r, float w) {
    a[0] = fmaf(__uint_as_float(r.x << 16), w, a[0]);
    a[1] = fmaf(__uint_as_float(r.x & 0xFFFF0000u), w, a[1]);
    a[2] = fmaf(__uint_as_float(r.y << 16), w, a[2]);
    a[3] = fmaf(__uint_as_float(r.y & 0xFFFF0000u), w, a[3]);
    a[4] = fmaf(__uint_as_float(r.z << 16), w, a[4]);
    a[5] = fmaf(__uint_as_float(r.z & 0xFFFF0000u), w, a[5]);
    a[6] = fmaf(__uint_as_float(r.w << 16), w, a[6]);
    a[7] = fmaf(__uint_as_float(r.w & 0xFFFF0000u), w, a[7]);
}

// ============================ fast binned path ============================

// Pass 1: stage chunk's src/dst in LDS (single global read); 2x-replicated LDS
// histograms (copy = tid&1, interleaved so copies sit in adjacent banks);
// reserve per-bucket ranges; append records from the LDS copies.
__global__ __launch_bounds__(256) void build1_kernel(
    const int* __restrict__ src, const int* __restrict__ dst,
    const float* __restrict__ ew,
    int* __restrict__ gCurD, int* __restrict__ gCurS,
    uint2* __restrict__ tempD, unsigned short* __restrict__ tempS) {
    __shared__ int lsrc[CHUNK];          // 12.5 KB
    __shared__ int ldst[CHUNK];          // 12.5 KB
    __shared__ int histD[NBUCK * 2], histS[NBUCK * 2];
    __shared__ int baseD[NBUCK], baseS[NBUCK];
    int tid = threadIdx.x;
    int cp = tid & 1;
    for (int i = tid; i < NBUCK; i += 256) {
        histD[i * 2] = 0; histD[i * 2 + 1] = 0;
        histS[i * 2] = 0; histS[i * 2 + 1] = 0;
    }
    int lo = blockIdx.x * CHUNK;
    for (int i = tid; i < CHUNK; i += 256) {   // coalesced single read
        lsrc[i] = src[lo + i];
        ldst[i] = dst[lo + i];
    }
    __syncthreads();
    for (int i = tid; i < CHUNK; i += 256) {
        atomicAdd(&histD[(ldst[i] >> 8) * 2 + cp], 1);
        atomicAdd(&histS[(lsrc[i] >> 8) * 2 + cp], 1);
    }
    __syncthreads();
    for (int i = tid; i < NBUCK; i += 256) {
        int d0 = histD[i * 2], d1 = histD[i * 2 + 1];
        baseD[i] = atomicAdd(&gCurD[i], d0 + d1);
        histD[i * 2] = 0; histD[i * 2 + 1] = d0;   // copy offsets within block range
        int s0 = histS[i * 2], s1 = histS[i * 2 + 1];
        baseS[i] = atomicAdd(&gCurS[i], s0 + s1);
        histS[i * 2] = 0; histS[i * 2 + 1] = s0;
    }
    __syncthreads();
    for (int i = tid; i < CHUNK; i += 256) {
        int s = lsrc[i], d = ldst[i];
        unsigned short wb = f2b(ew[lo + i]);
        int bd = d >> 8, bs = s >> 8;
        int pd = baseD[bd] + atomicAdd(&histD[bd * 2 + cp], 1);
        if (pd < CAP) tempD[(size_t)bd * CAP + pd] = make_uint2(((unsigned)s << 16) | wb, (unsigned)d);
        int ps = baseS[bs] + atomicAdd(&histS[bs * 2 + cp], 1);
        if (ps < CAP) tempS[(size_t)bs * CAP + ps] = (unsigned short)(s & 255);
    }
}

// Pass 2 (merged): blocks 0..195 = s-role (out-deg hist -> onorm, fused x->bf16
// convert); 196..391 = d-role (scatter records to padded edge slots, inorm);
// block 392 = W1/W2 -> bf16 transpose.
__global__ __launch_bounds__(512) void build2_kernel(
    const unsigned short* __restrict__ tempS, const int* __restrict__ gCurS,
    const uint2* __restrict__ tempD, const int* __restrict__ gCurD,
    const float* __restrict__ x, float* __restrict__ onorm,
    unsigned short* __restrict__ xs,
    unsigned* __restrict__ edges, int* __restrict__ cnt_in,
    float* __restrict__ inorm,
    const float* __restrict__ W1, const float* __restrict__ W2,
    unsigned short* __restrict__ Wt1, unsigned short* __restrict__ Wt2) {
    __shared__ int cur[256];
    __shared__ float on[256];
    int tid = threadIdx.x, b = blockIdx.x;

    if (b < NBUCK) {
        // ---- s-role ----
        if (tid < 256) cur[tid] = 0;
        __syncthreads();
        int n = min(gCurS[b], CAP);
        const unsigned short* rec = tempS + (size_t)b * CAP;
        for (int i = tid; i < n; i += 512) atomicAdd(&cur[rec[i]], 1);
        __syncthreads();
        if (tid < 256) {
            int node = (b << 8) + tid;
            float o = rsqrtf(fmaxf((float)cur[tid], 1.0f));
            on[tid] = o;
            if (node < NN) onorm[node] = o;
        }
        __syncthreads();
        #pragma unroll
        for (int k = 0; k < 8; ++k) {
            int t = tid + (k << 9);
            int r = t >> 4, sub = t & 15;
            int node = (b << 8) + r;
            if (node >= NN) continue;
            const float4* xv = (const float4*)(x + (size_t)node * DD + sub * 8);
            float o = on[r];
            float4 a = xv[0], c = xv[1];
            uint4 oo;
            oo.x = pack2(a.x * o, a.y * o);
            oo.y = pack2(a.z * o, a.w * o);
            oo.z = pack2(c.x * o, c.y * o);
            oo.w = pack2(c.z * o, c.w * o);
            ((uint4*)xs)[(size_t)node * 16 + sub] = oo;
        }
    } else if (b < 2 * NBUCK) {
        // ---- d-role ----
        int bb = b - NBUCK;
        if (tid < 256) cur[tid] = 0;
        __syncthreads();
        int n = min(gCurD[bb], CAP);
        const uint2* rec = tempD + (size_t)bb * CAP;
        for (int i = tid; i < n; i += 512) {
            uint2 r = rec[i];
            int d = (int)r.y;
            int slot = atomicAdd(&cur[d & 255], 1);
            if (slot < STRIDE) edges[(size_t)d * STRIDE + slot] = r.x;
        }
        __syncthreads();
        if (tid < 256) {
            int node = (bb << 8) + tid;
            if (node < NN) {
                int c = cur[tid];
                cnt_in[node] = min(c, STRIDE);
                inorm[node] = rsqrtf(fmaxf((float)c, 1.0f));
            }
        }
    } else {
        // ---- convw role: W[k][n] f32 -> Wt[n][k] bf16, both layers ----
        for (int idx = tid; idx < 2 * 16384; idx += 512) {
            const float* Ws = (idx < 16384) ? W1 : W2;
            unsigned short* Wd = (idx < 16384) ? Wt1 : Wt2;
            int i = idx & 16383;
            int k = i >> 7, n = i & 127;
            Wd[n * 128 + k] = f2b(Ws[i]);
        }
    }
}

// ==================== fused gather + MFMA-gemm kernel ====================
template<bool WRITE_HS>
__global__ __launch_bounds__(256) void fused_kernel(
    const unsigned short* __restrict__ hsrc, const unsigned* __restrict__ edges,
    const int* __restrict__ cnt, const unsigned short* __restrict__ Wt,
    const float* __restrict__ bias, const float* __restrict__ inorm,
    const float* __restrict__ onorm, const float* __restrict__ hres,
    float* __restrict__ out, unsigned short* __restrict__ hs) {
    __shared__ uint4 lsA[256];   // 16 rows x 16 uint4-chunks (chunk ^= row swizzle)

    int tid = threadIdx.x;
    int node0 = blockIdx.x * 16;

    // ---- phase 1: gather (unroll-8: 8 row-loads in flight per lane) ----
    {
        int nl = tid >> 4;        // node_local 0..15
        int lane = tid & 15;      // 16B slice of the 256B row
        int node = node0 + nl;
        int n = cnt[node];
        const uint4* rows = (const uint4*)hsrc;
        const unsigned* ep = edges + node * STRIDE;
        float acc[8] = {0.f,0.f,0.f,0.f,0.f,0.f,0.f,0.f};
        int i = 0;
        for (; i + 8 <= n; i += 8) {
            uint4 ea = *(const uint4*)(ep + i);
            uint4 eb = *(const uint4*)(ep + i + 4);
            uint4 r0 = rows[(ea.x >> 16) * 16 + lane];
            uint4 r1 = rows[(ea.y >> 16) * 16 + lane];
            uint4 r2 = rows[(ea.z >> 16) * 16 + lane];
            uint4 r3 = rows[(ea.w >> 16) * 16 + lane];
            uint4 r4 = rows[(eb.x >> 16) * 16 + lane];
            uint4 r5 = rows[(eb.y >> 16) * 16 + lane];
            uint4 r6 = rows[(eb.z >> 16) * 16 + lane];
            uint4 r7 = rows[(eb.w >> 16) * 16 + lane];
            acc8(acc, r0, b2f((unsigned short)(ea.x & 0xFFFFu)));
            acc8(acc, r1, b2f((unsigned short)(ea.y & 0xFFFFu)));
            acc8(acc, r2, b2f((unsigned short)(ea.z & 0xFFFFu)));
            acc8(acc, r3, b2f((unsigned short)(ea.w & 0xFFFFu)));
            acc8(acc, r4, b2f((unsigned short)(eb.x & 0xFFFFu)));
            acc8(acc, r5, b2f((unsigned short)(eb.y & 0xFFFFu)));
            acc8(acc, r6, b2f((unsigned short)(eb.z & 0xFFFFu)));
            acc8(acc, r7, b2f((unsigned short)(eb.w & 0xFFFFu)));
        }
        if (i + 4 <= n) {
            uint4 ea = *(const uint4*)(ep + i);
            uint4 r0 = rows[(ea.x >> 16) * 16 + lane];
            uint4 r1 = rows[(ea.y >> 16) * 16 + lane];
            uint4 r2 = rows[(ea.z >> 16) * 16 + lane];
            uint4 r3 = rows[(ea.w >> 16) * 16 + lane];
            acc8(acc, r0, b2f((unsigned short)(ea.x & 0xFFFFu)));
            acc8(acc, r1, b2f((unsigned short)(ea.y & 0xFFFFu)));
            acc8(acc, r2, b2f((unsigned short)(ea.z & 0xFFFFu)));
            acc8(acc, r3, b2f((unsigned short)(ea.w & 0xFFFFu)));
            i += 4;
        }
        for (; i < n; ++i) {
            unsigned wrd = ep[i];
            uint4 r = rows[(wrd >> 16) * 16 + lane];
            acc8(acc, r, b2f((unsigned short)(wrd & 0xFFFFu)));
        }
        uint4 p;
        p.x = pack2(acc[0], acc[1]);
        p.y = pack2(acc[2], acc[3]);
        p.z = pack2(acc[4], acc[5]);
        p.w = pack2(acc[6], acc[7]);
        lsA[nl * 16 + (lane ^ nl)] = p;   // swizzle kills 256B-stride bank conflict
    }
    __syncthreads();

    // ---- phase 2: MFMA ----
    int l = tid & 63;
    int w = tid >> 6;            // wave 0..3 -> cols [w*32, w*32+32)
    int r16 = l & 15;
    int q = l >> 4;

    const short8* lsAs = (const short8*)lsA;
    short8 afrag[4];
    #pragma unroll
    for (int kk = 0; kk < 4; ++kk) {
        int chunk = kk * 4 + q;
        afrag[kk] = lsAs[r16 * 16 + (chunk ^ r16)];
    }

    int col0 = w * 32 + r16;
    int col1 = col0 + 16;
    const uint4* wt4 = (const uint4*)Wt;
    f32x4 acc0 = {0.f, 0.f, 0.f, 0.f};
    f32x4 acc1 = {0.f, 0.f, 0.f, 0.f};
    #pragma unroll
    for (int kk = 0; kk < 4; ++kk) {
        int cidx = kk * 4 + q;
        uint4 bu0 = wt4[col0 * 16 + cidx];
        uint4 bu1 = wt4[col1 * 16 + cidx];
        short8 b0 = *(const short8*)&bu0;
        short8 b1 = *(const short8*)&bu1;
        acc0 = __builtin_amdgcn_mfma_f32_16x16x32_bf16(afrag[kk], b0, acc0, 0, 0, 0);
        acc1 = __builtin_amdgcn_mfma_f32_16x16x32_bf16(afrag[kk], b1, acc1, 0, 0, 0);
    }

    float bc0 = bias[col0], bc1 = bias[col1];
    #pragma unroll
    for (int reg = 0; reg < 4; ++reg) {
        int row = q * 4 + reg;           // C/D: col=lane&15, row=(lane>>4)*4+reg
        int n = node0 + row;
        float inr = inorm[n];
        size_t o0 = (size_t)n * DD + col0;
        size_t o1 = (size_t)n * DD + col1;
        float v0 = fmaxf(fmaf(acc0[reg], inr, bc0), 0.0f) + hres[o0];
        float v1 = fmaxf(fmaf(acc1[reg], inr, bc1), 0.0f) + hres[o1];
        out[o0] = v0;
        out[o1] = v1;
        if (WRITE_HS) {
            float on = onorm[n];
            hs[o0] = f2b(v0 * on);
            hs[o1] = f2b(v1 * on);
        }
    }
}

// ======================= CSR fallback path (small ws) =======================

__global__ void count_dst_kernel(const int* __restrict__ dst, int* __restrict__ cnt_dst) {
    int e = blockIdx.x * 256 + threadIdx.x;
    if (e < NE) atomicAdd(&cnt_dst[dst[e]], 1);
}

__global__ void scan1_kernel(const int* __restrict__ cnt, int* __restrict__ offs,
                             int* __restrict__ bsum) {
    __shared__ int s[256];
    int tid = threadIdx.x;
    int i = blockIdx.x * 256 + tid;
    int v = (i < NN) ? cnt[i] : 0;
    s[tid] = v;
    __syncthreads();
    #pragma unroll
    for (int off = 1; off < 256; off <<= 1) {
        int t = (tid >= off) ? s[tid - off] : 0;
        __syncthreads();
        s[tid] += t;
        __syncthreads();
    }
    if (i < NN) offs[i] = s[tid] - v;
    if (tid == 255) bsum[blockIdx.x] = s[255];
}

__global__ void scan2_kernel(int* __restrict__ bsum) {
    __shared__ int s[256];
    int tid = threadIdx.x;
    int v = (tid < SCAN_BLOCKS) ? bsum[tid] : 0;
    s[tid] = v;
    __syncthreads();
    #pragma unroll
    for (int off = 1; off < 256; off <<= 1) {
        int t = (tid >= off) ? s[tid - off] : 0;
        __syncthreads();
        s[tid] += t;
        __syncthreads();
    }
    if (tid < SCAN_BLOCKS) bsum[tid] = s[tid] - v;
}

__global__ void scan3_kernel(int* __restrict__ offs, const int* __restrict__ bsum) {
    int i = blockIdx.x * 256 + threadIdx.x;
    if (i < NN) offs[i] += bsum[blockIdx.x];
    if (i == 0) offs[NN] = NE;
}

__global__ void bucket_csr_kernel(const int* __restrict__ src, const int* __restrict__ dst,
                                  const float* __restrict__ ew, const int* __restrict__ offs,
                                  int* __restrict__ cursor, int* __restrict__ cnt_src,
                                  unsigned* __restrict__ edges) {
    int e = blockIdx.x * 256 + threadIdx.x;
    if (e >= NE) return;
    int s = src[e], d = dst[e];
    unsigned short wb = f2b(ew[e]);
    int pos = offs[d] + atomicAdd(&cursor[d], 1);
    edges[pos] = ((unsigned)s << 16) | (unsigned)wb;
    atomicAdd(&cnt_src[s], 1);
}

__global__ void norm_kernel(const int* __restrict__ cnt_src, const int* __restrict__ cursor,
                            float* __restrict__ onorm, float* __restrict__ inorm) {
    int i = blockIdx.x * 256 + threadIdx.x;
    if (i < NN) {
        onorm[i] = rsqrtf(fmaxf((float)cnt_src[i], 1.0f));
        inorm[i] = rsqrtf(fmaxf((float)cursor[i], 1.0f));
    }
}

__global__ void convert_kernel(const float* __restrict__ x, const float* __restrict__ onorm,
                               unsigned short* __restrict__ xs) {
    int idx = blockIdx.x * 256 + threadIdx.x;
    if (idx >= NN * DD / 8) return;
    const float4* xv = (const float4*)(x + (size_t)idx * 8);
    float on = onorm[idx >> 4];
    float4 a = xv[0], c = xv[1];
    uint4 o;
    o.x = pack2(a.x * on, a.y * on);
    o.y = pack2(a.z * on, a.w * on);
    o.z = pack2(c.x * on, c.y * on);
    o.w = pack2(c.z * on, c.w * on);
    ((uint4*)xs)[idx] = o;
}

template<bool PADDED>
__global__ __launch_bounds__(256) void gather_kernel(
    const unsigned short* __restrict__ hsrc, const unsigned* __restrict__ edges,
    const int* __restrict__ offs, const int* __restrict__ cnt,
    unsigned short* __restrict__ agg) {
    int t = blockIdx.x * 256 + threadIdx.x;
    int node = t >> 5;
    int lane = t & 31;
    if (node >= NN) return;
    int base = PADDED ? node * STRIDE : offs[node];
    int n = cnt[node];
    const ushort4* rows = (const ushort4*)hsrc;
    float4 acc = make_float4(0.f, 0.f, 0.f, 0.f);
    for (int i = 0; i < n; ++i) {
        unsigned wrd = edges[base + i];
        float w = b2f((unsigned short)(wrd & 0xFFFFu));
        ushort4 v = rows[(wrd >> 16) * 32 + lane];
        acc.x = fmaf(b2f(v.x), w, acc.x);
        acc.y = fmaf(b2f(v.y), w, acc.y);
        acc.z = fmaf(b2f(v.z), w, acc.z);
        acc.w = fmaf(b2f(v.w), w, acc.w);
    }
    ushort4 o;
    o.x = f2b(acc.x); o.y = f2b(acc.y); o.z = f2b(acc.z); o.w = f2b(acc.w);
    ((ushort4*)agg)[node * 32 + lane] = o;
}

template<bool WRITE_HS>
__global__ __launch_bounds__(256) void gemm_kernel(
    const unsigned short* __restrict__ agg, const float* __restrict__ inorm,
    const float* __restrict__ W, const float* __restrict__ b,
    const float* __restrict__ hres, float* __restrict__ out,
    const float* __restrict__ onorm, unsigned short* __restrict__ hs) {
    __shared__ float rows[16 * DD];

    int tid = threadIdx.x;
    int node0 = blockIdx.x * 16;

    uint4 t4 = ((const uint4*)(agg + (size_t)node0 * DD))[tid];
    int bidx = tid * 8;
    rows[bidx + 0] = b2f((unsigned short)(t4.x & 0xFFFFu));
    rows[bidx + 1] = b2f((unsigned short)(t4.x >> 16));
    rows[bidx + 2] = b2f((unsigned short)(t4.y & 0xFFFFu));
    rows[bidx + 3] = b2f((unsigned short)(t4.y >> 16));
    rows[bidx + 4] = b2f((unsigned short)(t4.z & 0xFFFFu));
    rows[bidx + 5] = b2f((unsigned short)(t4.z >> 16));
    rows[bidx + 6] = b2f((unsigned short)(t4.w & 0xFFFFu));
    rows[bidx + 7] = b2f((unsigned short)(t4.w >> 16));
    __syncthreads();

    int col = tid & 127;
    int mbase = (tid >> 7) * 8;
    float bcol = b[col];

    float acc[8] = {0.f,0.f,0.f,0.f,0.f,0.f,0.f,0.f};

    #pragma unroll 4
    for (int k = 0; k < DD; ++k) {
        float wkj = W[k * DD + col];
        #pragma unroll
        for (int m = 0; m < 8; ++m)
            acc[m] = fmaf(rows[(mbase + m) * DD + k], wkj, acc[m]);
    }

    #pragma unroll
    for (int m = 0; m < 8; ++m) {
        int n = node0 + mbase + m;
        float r = fmaxf(fmaf(acc[m], inorm[n], bcol), 0.0f) + hres[(size_t)n * DD + col];
        out[(size_t)n * DD + col] = r;
        if (WRITE_HS) hs[(size_t)n * DD + col] = f2b(r * onorm[n]);
    }
}

extern "C" void kernel_launch(void* const* d_in, const int* in_sizes, int n_in,
                              void* d_out, int out_size, void* d_ws, size_t ws_size,
                              hipStream_t stream) {
    const float* x  = (const float*)d_in[0];
    const float* ew = (const float*)d_in[1];
    const int*   src = (const int*)d_in[2];
    const int*   dst = (const int*)d_in[3];
    const float* W1 = (const float*)d_in[4];
    const float* b1 = (const float*)d_in[5];
    const float* W2 = (const float*)d_in[6];
    const float* b2 = (const float*)d_in[7];
    float* out = (float*)d_out;

    const int EB = (NE + 255) / 256;
    const int NB = (NN + 255) / 256;
    const int GB = (NN * 32 + 255) / 256;
    const int MB = NN / 16;                // 3125

    // fast-path arena:
    // bufA (xs, 12.8MB) | tempD(14.112MB) ∪ bufC(hs, 12.8MB) | edges(14.4MB) ∪ tempS(3.53MB)
    // | gCurD gCurS cnt_in inorm onorm | Wt1 Wt2 (bf16 32KB each)   total ≈ 42.0 MB
    size_t offA  = 0;
    size_t offT  = offA + (size_t)NN * DD * 2;                     // 12,800,000
    size_t offE  = offT + (size_t)NBUCK * CAP * 8;                 // +14,112,000
    size_t offI  = offE + (size_t)NN * STRIDE * 4;                 // +14,400,000
    size_t need  = offI + (2 * NBUCK + 3 * NN) * sizeof(int) + 2 * 16384 * 2;

    if (ws_size >= need) {
        unsigned short* bufA = (unsigned short*)((char*)d_ws + offA);
        uint2*    tempD = (uint2*)((char*)d_ws + offT);
        unsigned short* bufC = (unsigned short*)((char*)d_ws + offT); // post-build2
        unsigned* edges = (unsigned*)((char*)d_ws + offE);
        unsigned short* tempS = (unsigned short*)((char*)d_ws + offE); // pre-build2
        int* gCurD = (int*)((char*)d_ws + offI);
        int* gCurS = gCurD + NBUCK;
        int* cnt_in = gCurS + NBUCK;
        float* inorm = (float*)(cnt_in + NN);
        float* onorm = inorm + NN;
        unsigned short* Wt1 = (unsigned short*)(onorm + NN);
        unsigned short* Wt2 = Wt1 + 16384;

        hipMemsetAsync(gCurD, 0, 2 * NBUCK * sizeof(int), stream);
        build1_kernel<<<B1B, 256, 0, stream>>>(src, dst, ew, gCurD, gCurS, tempD, tempS);
        build2_kernel<<<2 * NBUCK + 1, 512, 0, stream>>>(
            tempS, gCurS, tempD, gCurD, x, onorm, bufA,
            edges, cnt_in, inorm, W1, W2, Wt1, Wt2);

        // layer 1: gather from bufA, hs -> bufC (tempD region, now dead)
        fused_kernel<true><<<MB, 256, 0, stream>>>(bufA, edges, cnt_in, Wt1, b1,
                                                   inorm, onorm, x, out, bufC);
        // layer 2: gather from bufC, residual aliased with out (safe)
        fused_kernel<false><<<MB, 256, 0, stream>>>(bufC, edges, cnt_in, Wt2, b2,
                                                    inorm, onorm, out, out, nullptr);
    } else {
        // exact-CSR fallback (~33MB)
        unsigned short* bufA = (unsigned short*)d_ws;
        unsigned short* bufB = bufA + (size_t)NN * DD;
        int* cnt_src = (int*)(bufB + (size_t)NN * DD);
        int* cursor  = cnt_src + NN;
        int* cnt_dst = cursor + NN;
        int* offs    = cnt_dst + NN;
        int* bsum    = offs + NN + 1;
        float* onorm = (float*)(bsum + 256);
        float* inorm = onorm + NN;
        unsigned* edges = (unsigned*)(inorm + NN);

        hipMemsetAsync(cnt_src, 0, 3 * NN * sizeof(int), stream);
        count_dst_kernel<<<EB, 256, 0, stream>>>(dst, cnt_dst);
        scan1_kernel<<<NB, 256, 0, stream>>>(cnt_dst, offs, bsum);
        scan2_kernel<<<1, 256, 0, stream>>>(bsum);
        scan3_kernel<<<NB, 256, 0, stream>>>(offs, bsum);
        bucket_csr_kernel<<<EB, 256, 0, stream>>>(src, dst, ew, offs, cursor, cnt_src, edges);
        norm_kernel<<<NB, 256, 0, stream>>>(cnt_src, cursor, onorm, inorm);
        convert_kernel<<<MB, 256, 0, stream>>>(x, onorm, bufA);

        gather_kernel<false><<<GB, 256, 0, stream>>>(bufA, edges, offs, cursor, bufB);
        gemm_kernel<true><<<MB, 256, 0, stream>>>(bufB, inorm, W1, b1, x, out, onorm, bufA);
        gather_kernel<false><<<GB, 256, 0, stream>>>(bufA, edges, offs, cursor, bufB);
        gemm_kernel<false><<<MB, 256, 0, stream>>>(bufB, inorm, W2, b2, out, out, onorm, nullptr);
    }
}